// Round 5
// baseline (1878.737 us; speedup 1.0000x reference)
//
#include <hip/hip_runtime.h>
#include <cstdint>
#include <cstddef>

typedef unsigned short u16;
typedef __attribute__((ext_vector_type(8))) __bf16 bf16x8;
typedef __attribute__((ext_vector_type(4))) float f32x4;

// fp32 -> bf16 round-to-nearest-even (inputs are well-behaved, no NaN path)
__device__ __forceinline__ u16 f2bf(float f) {
  union { float f; unsigned u; } v; v.f = f;
  unsigned r = v.u + 0x7FFFu + ((v.u >> 16) & 1u);
  return (u16)(r >> 16);
}
__device__ __forceinline__ float bf2f(unsigned h) {
  union { unsigned u; float f; } v; v.u = h << 16;
  return v.f;
}

// ---------------------------------------------------------------- subdom loss
__global__ void init_loss_kernel(const float* __restrict__ c,
                                 const int* __restrict__ D,
                                 const int* __restrict__ K,
                                 float* __restrict__ out) {
  out[0] = -c[0] * (float)D[0] * (float)K[0];
}

__global__ void subdom_kernel(const float4* __restrict__ dm,
                              const float4* __restrict__ sl,
                              const float4* __restrict__ alpha4,
                              float* __restrict__ out, int n4, int k4mask) {
  const int stride = gridDim.x * blockDim.x;
  float s = 0.f;
  for (int i = blockIdx.x * blockDim.x + threadIdx.x; i < n4; i += stride) {
    float4 d = dm[i], l = sl[i], a = alpha4[i & k4mask];
    s += fmaxf(fmaf(a.x, l.x - d.x, 1.f), 0.f);
    s += fmaxf(fmaf(a.y, l.y - d.y, 1.f), 0.f);
    s += fmaxf(fmaf(a.z, l.z - d.z, 1.f), 0.f);
    s += fmaxf(fmaf(a.w, l.w - d.w, 1.f), 0.f);
  }
#pragma unroll
  for (int off = 32; off > 0; off >>= 1) s += __shfl_down(s, off, 64);
  __shared__ float red[4];
  const int lane = threadIdx.x & 63, wave = threadIdx.x >> 6;
  if (lane == 0) red[wave] = s;
  __syncthreads();
  if (threadIdx.x == 0) atomicAdd(out, red[0] + red[1] + red[2] + red[3]);
}

// ---------------------------------------------------------------- casts
__global__ void cast_f32_bf16_kernel(const float4* __restrict__ in,
                                     u16* __restrict__ out, int n4) {
  const int stride = gridDim.x * blockDim.x;
  for (int i = blockIdx.x * blockDim.x + threadIdx.x; i < n4; i += stride) {
    float4 v = in[i];
    uint2 p;
    p.x = (unsigned)f2bf(v.x) | ((unsigned)f2bf(v.y) << 16);
    p.y = (unsigned)f2bf(v.z) | ((unsigned)f2bf(v.w) << 16);
    ((uint2*)out)[i] = p;
  }
}

// in: [K,N] fp32 row-major  ->  out: [N,K] bf16 row-major
__global__ void transpose_cast_kernel(const float* __restrict__ in,
                                      u16* __restrict__ out, int K, int N) {
  __shared__ float tile[32][33];
  const int bx = blockIdx.x * 32;  // N
  const int by = blockIdx.y * 32;  // K
  const int tx = threadIdx.x, ty = threadIdx.y;
#pragma unroll
  for (int i = ty; i < 32; i += 8)
    tile[i][tx] = in[(size_t)(by + i) * N + bx + tx];
  __syncthreads();
#pragma unroll
  for (int i = ty; i < 32; i += 8)
    out[(size_t)(bx + i) * K + by + tx] = f2bf(tile[tx][i]);
}

// ---------------------------------------------------------------- GEMM
// 256x256 tile, BK=64, 8 waves (2Mx4N), 8-phase C-quadrant schedule, v5.
//
// v5 vs v4 (round 4: 45% MfmaUtil; frag ds_reads sat immediately in front
// of the MFMAs that consume them -> LDS issue+latency on the critical path,
// 2 waves/SIMD can't hide it):
//  * ALL fragment reads moved to AFTER the MFMA cluster, one phase ahead of
//    first use, into the SAME register banks (WAR on the same variables;
//    sched_barrier(0) after the MFMAs stops SSA-rename hoisting).  Zero
//    VGPR growth -- we sit at exactly 256 unified regs (128 VGPR+128 acc),
//    the 2-wave/SIMD residency edge.
//  * af bank rotation: holds A(0,e) for ph1,2; reloaded end-ph2 -> A(0,o)
//    for ph3,4; end-ph4 -> A(1,e); end-ph6 -> A(1,o); end-ph8 -> next tile.
//    bfr0: B(#,nh0) for ph1&3 / 5&7, reloaded end-ph4/ph8; bfr1: B(#,nh1)
//    for ph2&4 / 6&8, reloaded end-ph1/ph5.
//  * Stages consolidated: 4 loads at ph1 (A1e+B10), ph2 (B11+A1o),
//    ph5 (A0e'+B00'), ph6 (B01'+A0o').  Ledger (simulated, prologue/it0/
//    steady/tail): waits [4,-,4,2,4,-,4,2]; stage->wait slack >=2 phases
//    (>=1300cy >= HBM ~900); every region overwrite >=4 barriers after its
//    last read; every read's region published exactly 1 barrier earlier.
//  Tail: waits [4,-,4,2,0,-,-,-], no t2 stages, no end-ph8 reads.

__device__ __forceinline__ void gload_lds16(const void* g, void* l) {
  __builtin_amdgcn_global_load_lds(
      (const __attribute__((address_space(1))) void*)g,
      (__attribute__((address_space(3))) void*)l, 16, 0, 0);
}

#define VMW(N) asm volatile("s_waitcnt vmcnt(" #N ")" ::: "memory")
#define MF(a, b, c) __builtin_amdgcn_mfma_f32_16x16x32_bf16(a, b, c, 0, 0, 0)

// one instr: stage A quarter Q (rows Q*64..+63) of k-tile TK into buf BU
#define STAGE_A(BU, Q, TK)                                                    \
  gload_lds16(A + aGbase + (size_t)((Q)*64) * K + (size_t)(TK)*64,            \
              (void*)(As + ((BU)*4 + (Q)) * 4096 + swave))

// one instr: stage B nh-half NH, h-part HH (rows wn-major) of k-tile TK
#define STAGE_B(BU, NH, HH, TK)                                               \
  gload_lds16(Bt + bGbase + (size_t)((NH)*32 + (HH)*128) * K +                \
                  (size_t)(TK)*64,                                            \
              (void*)(Bs + ((BU)*2 + (NH)) * 8192 + (HH)*4096 + swave))

// read 8 A-frags of region (BU, wm2+MH) into the af bank
#define ARD(BU, MH)                                                           \
  {                                                                           \
    const u16* Ar_ = As + ((BU)*4 + wm2 + (MH)) * 4096 + abase;               \
    _Pragma("unroll") for (int f_ = 0; f_ < 4; ++f_) {                        \
      af0[f_] = *(const bf16x8*)(Ar_ + f_ * 1024 + aslot0);                   \
      af1[f_] = *(const bf16x8*)(Ar_ + f_ * 1024 + aslot1);                   \
    }                                                                         \
  }

// read 4 B-frags of region (BU, NH2) into bank BF
#define BRD(BF, BU, NH2)                                                      \
  {                                                                           \
    const u16* Br_ = Bs + ((BU)*2 + (NH2)) * 8192 + bbase;                    \
    BF[0] = *(const bf16x8*)(Br_ + aslot0);                                   \
    BF[1] = *(const bf16x8*)(Br_ + aslot1);                                   \
    BF[2] = *(const bf16x8*)(Br_ + 1024 + aslot0);                            \
    BF[3] = *(const bf16x8*)(Br_ + 1024 + aslot1);                            \
  }

// One phase: [stage] [MFMA x16 (inputs pre-read)] [next-phase frag reads]
//            [counted wait] [barrier]
#define PH(MH, NH, BF, STAGE_CODE, POST_CODE, WAIT_CODE)                      \
  {                                                                           \
    STAGE_CODE;                                                               \
    __builtin_amdgcn_s_setprio(1);                                            \
    _Pragma("unroll") for (int f_ = 0; f_ < 4; ++f_) {                        \
      acc[(MH)*4 + f_][(NH)*2 + 0] = MF(af0[f_], BF[0], acc[(MH)*4 + f_][(NH)*2 + 0]); \
      acc[(MH)*4 + f_][(NH)*2 + 0] = MF(af1[f_], BF[1], acc[(MH)*4 + f_][(NH)*2 + 0]); \
      acc[(MH)*4 + f_][(NH)*2 + 1] = MF(af0[f_], BF[2], acc[(MH)*4 + f_][(NH)*2 + 1]); \
      acc[(MH)*4 + f_][(NH)*2 + 1] = MF(af1[f_], BF[3], acc[(MH)*4 + f_][(NH)*2 + 1]); \
    }                                                                         \
    __builtin_amdgcn_s_setprio(0);                                            \
    __builtin_amdgcn_sched_barrier(0);                                        \
    POST_CODE;                                                                \
    WAIT_CODE;                                                                \
    __builtin_amdgcn_s_barrier();                                             \
  }

// C[M,N] = act(A[M,K] @ Bt[N,K]^T + bias), bf16 in/out, fp32 accumulate.
// Requires M%256==0, N%256==0, K%128==0.
__global__ __launch_bounds__(512, 2) void gemm256(
    const u16* __restrict__ A, const u16* __restrict__ Bt,
    const float* __restrict__ bias, u16* __restrict__ C,
    int M, int N, int K, int act) {
  __shared__ __align__(16) u16 As[2 * 4 * 4096];  // 64 KB
  __shared__ __align__(16) u16 Bs[2 * 2 * 8192];  // 64 KB

  // XCD-aware block swizzle (nwg % 8 == 0 for all our grids)
  const int gx = gridDim.x;
  const int bid = blockIdx.x + blockIdx.y * gx;
  const int cpx = (gx * gridDim.y) >> 3;
  const int tilei = (bid & 7) * cpx + (bid >> 3);
  const int m0 = (tilei / gx) * 256;
  const int n0 = (tilei % gx) * 256;

  const int tid = threadIdx.x;
  const int wave = tid >> 6, lane = tid & 63;
  const int l15 = lane & 15, quad = lane >> 4;
  const int wm = wave >> 2, wn = wave & 3;  // 2 x 4 wave grid, 128x64 each
  const int wm2 = wm << 1;
  const int lsw = l15 & 7;

  // frag-read addresses (u16 elements), slot = (ks*4+quad) ^ (row&7)
  const int aslot0 = ((quad ^ lsw) << 3);        // ks=0
  const int aslot1 = (((4 + quad) ^ lsw) << 3);  // ks=1
  const int abase = l15 * 64;                    // + region + f*1024 + aslot
  const int bbase = (wn * 32 + l15) * 64;        // + region + j2*1024 + aslot

  // staging: thread t owns chunk c=t of an 8KB piece; LDS linear (c*8),
  // global k-chunk = (c&7) ^ ((c>>3)&7)  (both-sides involution)
  const int srow = tid >> 3;
  const int skch = ((tid & 7) ^ (srow & 7)) << 3;
  const int brow = ((srow >> 5) << 6) + (srow & 31);  // B row reorder (wn-major)
  const size_t aGbase = (size_t)(m0 + srow) * K + skch;
  const size_t bGbase = (size_t)(n0 + brow) * K + skch;
  const int swave = wave * 512;  // LDS elems, wave-uniform dest base

  f32x4 acc[8][4];
#pragma unroll
  for (int i = 0; i < 8; ++i)
#pragma unroll
    for (int j = 0; j < 4; ++j) acc[i][j] = (f32x4){0.f, 0.f, 0.f, 0.f};
  bf16x8 af0[4], af1[4], bfr0[4], bfr1[4];

  // prologue: stage buf0 <- tile 0 in order [A0e, B00, B01, A0o];
  // VMW(2) publishes all but A0o; barrier; pre-read ph1's frags.
  STAGE_A(0, 0, 0); STAGE_A(0, 2, 0);
  STAGE_B(0, 0, 0, 0); STAGE_B(0, 0, 1, 0);
  STAGE_B(0, 1, 0, 0); STAGE_B(0, 1, 1, 0);
  STAGE_A(0, 1, 0); STAGE_A(0, 3, 0);
  VMW(2);
  __builtin_amdgcn_s_barrier();
  ARD(0, 0);
  BRD(bfr0, 0, 0);

  const int niter = K >> 7;  // 2 K-tiles (BK=64) per iteration
  for (int it = 0; it < niter - 1; ++it) {
    const int t1 = 2 * it + 1, t2 = 2 * it + 2;
    PH(0, 0, bfr0,
       { STAGE_A(1, 0, t1); STAGE_A(1, 2, t1);
         STAGE_B(1, 0, 0, t1); STAGE_B(1, 0, 1, t1); },
       { BRD(bfr1, 0, 1); }, { VMW(4); });
    PH(0, 1, bfr1,
       { STAGE_B(1, 1, 0, t1); STAGE_B(1, 1, 1, t1);
         STAGE_A(1, 1, t1); STAGE_A(1, 3, t1); },
       { ARD(0, 1); }, {});
    PH(1, 0, bfr0, {}, {}, { VMW(4); });
    PH(1, 1, bfr1, {}, { ARD(1, 0); BRD(bfr0, 1, 0); }, { VMW(2); });
    PH(0, 0, bfr0,
       { STAGE_A(0, 0, t2); STAGE_A(0, 2, t2);
         STAGE_B(0, 0, 0, t2); STAGE_B(0, 0, 1, t2); },
       { BRD(bfr1, 1, 1); }, { VMW(4); });
    PH(0, 1, bfr1,
       { STAGE_B(0, 1, 0, t2); STAGE_B(0, 1, 1, t2);
         STAGE_A(0, 1, t2); STAGE_A(0, 3, t2); },
       { ARD(1, 1); }, {});
    PH(1, 0, bfr0, {}, {}, { VMW(4); });
    PH(1, 1, bfr1, {}, { ARD(0, 0); BRD(bfr0, 0, 0); }, { VMW(2); });
  }
  {  // peeled last iteration: no t2 stages, no next-tile reads
    const int t1 = 2 * niter - 1;
    PH(0, 0, bfr0,
       { STAGE_A(1, 0, t1); STAGE_A(1, 2, t1);
         STAGE_B(1, 0, 0, t1); STAGE_B(1, 0, 1, t1); },
       { BRD(bfr1, 0, 1); }, { VMW(4); });
    PH(0, 1, bfr1,
       { STAGE_B(1, 1, 0, t1); STAGE_B(1, 1, 1, t1);
         STAGE_A(1, 1, t1); STAGE_A(1, 3, t1); },
       { ARD(0, 1); }, {});
    PH(1, 0, bfr0, {}, {}, { VMW(4); });
    PH(1, 1, bfr1, {}, { ARD(1, 0); BRD(bfr0, 1, 0); }, { VMW(2); });
    PH(0, 0, bfr0, {}, { BRD(bfr1, 1, 1); }, { VMW(0); });
    PH(0, 1, bfr1, {}, { ARD(1, 1); }, {});
    PH(1, 0, bfr0, {}, {}, {});
    PH(1, 1, bfr1, {}, {}, {});
  }

  // epilogue: C/D layout col=lane&15, row=quad*4+reg (m89-verified)
#pragma unroll
  for (int mi = 0; mi < 8; ++mi) {
    const int row = m0 + wm * 128 + (mi >> 2) * 64 + (mi & 3) * 16 + quad * 4;
#pragma unroll
    for (int j = 0; j < 4; ++j) {
      const int col = n0 + wn * 64 + j * 16 + l15;
      const float bv = bias[col];
#pragma unroll
      for (int r = 0; r < 4; ++r) {
        float v = acc[mi][j][r] + bv;
        if (act) v = fmaxf(v, 0.f);
        C[(size_t)(row + r) * N + col] = f2bf(v);
      }
    }
  }
}

// ---------------------------------------------------------------- head: h@W4+b4, sigmoid
__global__ __launch_bounds__(256) void head_kernel(
    const u16* __restrict__ h, const float2* __restrict__ W4,
    const float* __restrict__ b4, float* __restrict__ out, int H) {
  const int row = blockIdx.x;
  const u16* hr = h + (size_t)row * H;
  const int tid = threadIdx.x;
  float p0 = 0.f, p1 = 0.f;
#pragma unroll
  for (int ii = 0; ii < 2; ++ii) {
    const int base = tid * 16 + ii * 8;  // 8 bf16 per uint4
    const uint4 hv = *(const uint4*)(hr + base);
    const unsigned uu[4] = {hv.x, hv.y, hv.z, hv.w};
#pragma unroll
    for (int j = 0; j < 4; ++j) {
      float a0 = bf2f(uu[j] & 0xffffu);
      float a1 = bf2f(uu[j] >> 16);
      float2 w0 = W4[base + 2 * j];
      float2 w1 = W4[base + 2 * j + 1];
      p0 += a0 * w0.x + a1 * w1.x;
      p1 += a0 * w0.y + a1 * w1.y;
    }
  }
#pragma unroll
  for (int off = 32; off > 0; off >>= 1) {
    p0 += __shfl_down(p0, off, 64);
    p1 += __shfl_down(p1, off, 64);
  }
  __shared__ float r0[4], r1[4];
  const int lane = tid & 63, wave = tid >> 6;
  if (lane == 0) { r0[wave] = p0; r1[wave] = p1; }
  __syncthreads();
  if (tid == 0) {
    float l0 = r0[0] + r0[1] + r0[2] + r0[3] + b4[0];
    float l1 = r1[0] + r1[1] + r1[2] + r1[3] + b4[1];
    out[1 + row * 2] = 1.f / (1.f + __expf(-l0));
    out[2 + row * 2] = 1.f / (1.f + __expf(-l1));
  }
}

// ---------------------------------------------------------------- launch
extern "C" void kernel_launch(void* const* d_in, const int* in_sizes, int n_in,
                              void* d_out, int out_size, void* d_ws,
                              size_t ws_size, hipStream_t stream) {
  (void)in_sizes; (void)n_in; (void)out_size; (void)ws_size;
  const float* x  = (const float*)d_in[0];
  const float* dm = (const float*)d_in[1];
  const float* al = (const float*)d_in[2];
  const float* sl = (const float*)d_in[3];
  const float* sc = (const float*)d_in[4];
  const int*   nd = (const int*)d_in[5];
  const int*   nf = (const int*)d_in[6];
  const float* W1 = (const float*)d_in[7];
  const float* b1 = (const float*)d_in[8];
  const float* W2 = (const float*)d_in[9];
  const float* b2 = (const float*)d_in[10];
  const float* W3 = (const float*)d_in[11];
  const float* b3 = (const float*)d_in[12];
  const float* W4 = (const float*)d_in[13];
  const float* b4 = (const float*)d_in[14];
  float* out = (float*)d_out;

  const int B = 16384, F = 2048, H = 4096, D = 4096, K = 2048;

  // workspace layout (352 MB): xb | wt | hA | hB
  char* ws = (char*)d_ws;
  u16* xb = (u16*)ws;                                         // B*F bf16
  u16* wt = (u16*)(ws + (size_t)B * F * 2);                   // H*H bf16 (reused W1t/W2t/W3t)
  u16* hA = (u16*)(ws + (size_t)B * F * 2 + (size_t)H * H * 2);
  u16* hB = hA + (size_t)B * H;

  // loss
  init_loss_kernel<<<1, 1, 0, stream>>>(sc, nd, nf, out);
  subdom_kernel<<<1024, 256, 0, stream>>>((const float4*)dm, (const float4*)sl,
                                          (const float4*)al, out, D * K / 4,
                                          K / 4 - 1);
  // MLP
  cast_f32_bf16_kernel<<<4096, 256, 0, stream>>>((const float4*)x, xb, B * F / 4);
  transpose_cast_kernel<<<dim3(H / 32, F / 32), dim3(32, 8), 0, stream>>>(W1, wt, F, H);
  gemm256<<<dim3(H / 256, B / 256), 512, 0, stream>>>(xb, wt, b1, hA, B, H, F, 1);
  transpose_cast_kernel<<<dim3(H / 32, H / 32), dim3(32, 8), 0, stream>>>(W2, wt, H, H);
  gemm256<<<dim3(H / 256, B / 256), 512, 0, stream>>>(hA, wt, b2, hB, B, H, H, 1);
  transpose_cast_kernel<<<dim3(H / 32, H / 32), dim3(32, 8), 0, stream>>>(W3, wt, H, H);
  gemm256<<<dim3(H / 256, B / 256), 512, 0, stream>>>(hB, wt, b3, hA, B, H, H, 1);
  head_kernel<<<B, 256, 0, stream>>>(hA, (const float2*)W4, b4, out, H);
}

// Round 6
// 1529.367 us; speedup vs baseline: 1.2284x; 1.2284x over previous
//
#include <hip/hip_runtime.h>
#include <cstdint>
#include <cstddef>

typedef unsigned short u16;
typedef __attribute__((ext_vector_type(8))) __bf16 bf16x8;
typedef __attribute__((ext_vector_type(4))) float f32x4;

// fp32 -> bf16 round-to-nearest-even (inputs are well-behaved, no NaN path)
__device__ __forceinline__ u16 f2bf(float f) {
  union { float f; unsigned u; } v; v.f = f;
  unsigned r = v.u + 0x7FFFu + ((v.u >> 16) & 1u);
  return (u16)(r >> 16);
}
__device__ __forceinline__ float bf2f(unsigned h) {
  union { unsigned u; float f; } v; v.u = h << 16;
  return v.f;
}

// ---------------------------------------------------------------- subdom loss
__global__ void init_loss_kernel(const float* __restrict__ c,
                                 const int* __restrict__ D,
                                 const int* __restrict__ K,
                                 float* __restrict__ out) {
  out[0] = -c[0] * (float)D[0] * (float)K[0];
}

__global__ void subdom_kernel(const float4* __restrict__ dm,
                              const float4* __restrict__ sl,
                              const float4* __restrict__ alpha4,
                              float* __restrict__ out, int n4, int k4mask) {
  const int stride = gridDim.x * blockDim.x;
  float s = 0.f;
  for (int i = blockIdx.x * blockDim.x + threadIdx.x; i < n4; i += stride) {
    float4 d = dm[i], l = sl[i], a = alpha4[i & k4mask];
    s += fmaxf(fmaf(a.x, l.x - d.x, 1.f), 0.f);
    s += fmaxf(fmaf(a.y, l.y - d.y, 1.f), 0.f);
    s += fmaxf(fmaf(a.z, l.z - d.z, 1.f), 0.f);
    s += fmaxf(fmaf(a.w, l.w - d.w, 1.f), 0.f);
  }
#pragma unroll
  for (int off = 32; off > 0; off >>= 1) s += __shfl_down(s, off, 64);
  __shared__ float red[4];
  const int lane = threadIdx.x & 63, wave = threadIdx.x >> 6;
  if (lane == 0) red[wave] = s;
  __syncthreads();
  if (threadIdx.x == 0) atomicAdd(out, red[0] + red[1] + red[2] + red[3]);
}

// ---------------------------------------------------------------- casts
__global__ void cast_f32_bf16_kernel(const float4* __restrict__ in,
                                     u16* __restrict__ out, int n4) {
  const int stride = gridDim.x * blockDim.x;
  for (int i = blockIdx.x * blockDim.x + threadIdx.x; i < n4; i += stride) {
    float4 v = in[i];
    uint2 p;
    p.x = (unsigned)f2bf(v.x) | ((unsigned)f2bf(v.y) << 16);
    p.y = (unsigned)f2bf(v.z) | ((unsigned)f2bf(v.w) << 16);
    ((uint2*)out)[i] = p;
  }
}

// in: [K,N] fp32 row-major  ->  out: [N,K] bf16 row-major
__global__ void transpose_cast_kernel(const float* __restrict__ in,
                                      u16* __restrict__ out, int K, int N) {
  __shared__ float tile[32][33];
  const int bx = blockIdx.x * 32;  // N
  const int by = blockIdx.y * 32;  // K
  const int tx = threadIdx.x, ty = threadIdx.y;
#pragma unroll
  for (int i = ty; i < 32; i += 8)
    tile[i][tx] = in[(size_t)(by + i) * N + bx + tx];
  __syncthreads();
#pragma unroll
  for (int i = ty; i < 32; i += 8)
    out[(size_t)(bx + i) * K + by + tx] = f2bf(tile[tx][i]);
}

// ---------------------------------------------------------------- GEMM
// 256x256 tile, BK=64, 8 waves (2Mx4N), v6: 4 MEGA-phases per 2 K-tiles.
//
// v6 vs v4 (best known, 531us GEMM2/3): v4 paid 8 barriers + 6 counted
// waits per 2 K-tiles; MFMA (1242cy/CU/iter) and LDS (~1100-1500cy) are
// balanced, so sync overhead is the remaining pole (v3->v4 barrier removal
// = -10% evidences this).  v6 merges to 4 phases of 32 MFMA each -- free,
// because bfr0/bfr1 are already held across both M-halves: same register
// banks, reads-at-top (fine-grained lgkmcnt interleave -- v5's post-MFMA
// reads + sched_barrier regressed 16%, reverted), one end barrier, setprio.
//
// Phase map (steady iter: tiles t0->buf0, t1->buf1; t2=t0+2, t3=t1+2):
//   M1: read[bfr0<-B(0,nh0), af<-A(0,wm2), bfr1<-B(0,nh1)]; stage buf1.A(t1);
//       MFMA32(MH0); VMW(8); bar     [retires A-odd(t0) for M2]
//   M2: read[af<-A(0,wm2+1)]; MFMA32(MH1); VMW(0); bar
//       [retires buf1.B(t1)+buf1.A(t1), all >=1.5 phases old, for M3]
//   M3: read[bfr0<-B(1,nh0), af<-A(1,wm2), bfr1<-B(1,nh1)];
//       stage buf0.B(t2)x4 + buf0.A-even(t2)x2; MFMA32(MH0); bar (no wait)
//   M4: read[af<-A(1,wm2+1)]; stage buf0.A-odd(t2)x2 + buf1.B(t3)x4;
//       MFMA32(MH1); VMW(6); bar     [retires M3's 6 for next M1]
// Ledger (per-wave in-flight): 6 ->10 ->8 ->0 ->6 ->12 ->6.  Every wait
// retires exactly the regions read next phase; every LDS overwrite >=1
// barrier after its region's last ds_read (reads are MFMA-consumed, so
// lgkmcnt drains before the barrier).  Tail: skip t2/t3 stages (nl guard),
// waits unchanged (trivially satisfied).  No peel needed.

__device__ __forceinline__ void gload_lds16(const void* g, void* l) {
  __builtin_amdgcn_global_load_lds(
      (const __attribute__((address_space(1))) void*)g,
      (__attribute__((address_space(3))) void*)l, 16, 0, 0);
}

#define VMW(N) asm volatile("s_waitcnt vmcnt(" #N ")" ::: "memory")
#define MF(a, b, c) __builtin_amdgcn_mfma_f32_16x16x32_bf16(a, b, c, 0, 0, 0)

// one instr: stage A quarter Q (rows Q*64..+63) of k-tile TK into buf BU
#define STAGE_A(BU, Q, TK)                                                    \
  gload_lds16(A + aGbase + (size_t)((Q)*64) * K + (size_t)(TK)*64,            \
              (void*)(As + ((BU)*4 + (Q)) * 4096 + swave))

// one instr: stage B nh-half NH, h-part HH (rows wn-major) of k-tile TK
#define STAGE_B(BU, NH, HH, TK)                                               \
  gload_lds16(Bt + bGbase + (size_t)((NH)*32 + (HH)*128) * K +                \
                  (size_t)(TK)*64,                                            \
              (void*)(Bs + ((BU)*2 + (NH)) * 8192 + (HH)*4096 + swave))

// read 8 A-frags of region (BU, wm2+MH) into the af bank
#define ARD(BU, MH)                                                           \
  {                                                                           \
    const u16* Ar_ = As + ((BU)*4 + wm2 + (MH)) * 4096 + abase;               \
    _Pragma("unroll") for (int f_ = 0; f_ < 4; ++f_) {                        \
      af0[f_] = *(const bf16x8*)(Ar_ + f_ * 1024 + aslot0);                   \
      af1[f_] = *(const bf16x8*)(Ar_ + f_ * 1024 + aslot1);                   \
    }                                                                         \
  }

// read 4 B-frags of region (BU, NH2) into bank BF
#define BRD(BF, BU, NH2)                                                      \
  {                                                                           \
    const u16* Br_ = Bs + ((BU)*2 + (NH2)) * 8192 + bbase;                    \
    BF[0] = *(const bf16x8*)(Br_ + aslot0);                                   \
    BF[1] = *(const bf16x8*)(Br_ + aslot1);                                   \
    BF[2] = *(const bf16x8*)(Br_ + 1024 + aslot0);                            \
    BF[3] = *(const bf16x8*)(Br_ + 1024 + aslot1);                            \
  }

// 32 MFMA: M-half MH x both N-halves, K=64 (af x bfr0 | af x bfr1)
#define MFMA32(MH)                                                            \
  __builtin_amdgcn_s_setprio(1);                                              \
  _Pragma("unroll") for (int f_ = 0; f_ < 4; ++f_) {                          \
    acc[(MH)*4 + f_][0] = MF(af0[f_], bfr0[0], acc[(MH)*4 + f_][0]);          \
    acc[(MH)*4 + f_][0] = MF(af1[f_], bfr0[1], acc[(MH)*4 + f_][0]);          \
    acc[(MH)*4 + f_][1] = MF(af0[f_], bfr0[2], acc[(MH)*4 + f_][1]);          \
    acc[(MH)*4 + f_][1] = MF(af1[f_], bfr0[3], acc[(MH)*4 + f_][1]);          \
    acc[(MH)*4 + f_][2] = MF(af0[f_], bfr1[0], acc[(MH)*4 + f_][2]);          \
    acc[(MH)*4 + f_][2] = MF(af1[f_], bfr1[1], acc[(MH)*4 + f_][2]);          \
    acc[(MH)*4 + f_][3] = MF(af0[f_], bfr1[2], acc[(MH)*4 + f_][3]);          \
    acc[(MH)*4 + f_][3] = MF(af1[f_], bfr1[3], acc[(MH)*4 + f_][3]);          \
  }                                                                           \
  __builtin_amdgcn_s_setprio(0);

// C[M,N] = act(A[M,K] @ Bt[N,K]^T + bias), bf16 in/out, fp32 accumulate.
// Requires M%256==0, N%256==0, K%256==0.
__global__ __launch_bounds__(512, 2) void gemm256(
    const u16* __restrict__ A, const u16* __restrict__ Bt,
    const float* __restrict__ bias, u16* __restrict__ C,
    int M, int N, int K, int act) {
  __shared__ __align__(16) u16 As[2 * 4 * 4096];  // 64 KB
  __shared__ __align__(16) u16 Bs[2 * 2 * 8192];  // 64 KB

  // XCD-aware block swizzle (nwg % 8 == 0 for all our grids)
  const int gx = gridDim.x;
  const int bid = blockIdx.x + blockIdx.y * gx;
  const int cpx = (gx * gridDim.y) >> 3;
  const int tilei = (bid & 7) * cpx + (bid >> 3);
  const int m0 = (tilei / gx) * 256;
  const int n0 = (tilei % gx) * 256;

  const int tid = threadIdx.x;
  const int wave = tid >> 6, lane = tid & 63;
  const int l15 = lane & 15, quad = lane >> 4;
  const int wm = wave >> 2, wn = wave & 3;  // 2 x 4 wave grid, 128x64 each
  const int wm2 = wm << 1;
  const int lsw = l15 & 7;

  // frag-read addresses (u16 elements), slot = (ks*4+quad) ^ (row&7)
  const int aslot0 = ((quad ^ lsw) << 3);        // ks=0
  const int aslot1 = (((4 + quad) ^ lsw) << 3);  // ks=1
  const int abase = l15 * 64;                    // + region + f*1024 + aslot
  const int bbase = (wn * 32 + l15) * 64;        // + region + j2*1024 + aslot

  // staging: thread t owns chunk c=t of an 8KB piece; LDS linear (c*8),
  // global k-chunk = (c&7) ^ ((c>>3)&7)  (both-sides involution)
  const int srow = tid >> 3;
  const int skch = ((tid & 7) ^ (srow & 7)) << 3;
  const int brow = ((srow >> 5) << 6) + (srow & 31);  // B row reorder (wn-major)
  const size_t aGbase = (size_t)(m0 + srow) * K + skch;
  const size_t bGbase = (size_t)(n0 + brow) * K + skch;
  const int swave = wave * 512;  // LDS elems, wave-uniform dest base

  f32x4 acc[8][4];
#pragma unroll
  for (int i = 0; i < 8; ++i)
#pragma unroll
    for (int j = 0; j < 4; ++j) acc[i][j] = (f32x4){0.f, 0.f, 0.f, 0.f};
  bf16x8 af0[4], af1[4], bfr0[4], bfr1[4];

  // prologue: buf0(t0) in order [A-even, B, A-odd] + buf1.B(t1);
  // VMW(6) publishes A-even+B (M1-top needs); in-flight = {A-odd, b1B} = 6
  // = exact steady entry state.
  STAGE_A(0, 0, 0); STAGE_A(0, 2, 0);
  STAGE_B(0, 0, 0, 0); STAGE_B(0, 0, 1, 0);
  STAGE_B(0, 1, 0, 0); STAGE_B(0, 1, 1, 0);
  STAGE_A(0, 1, 0); STAGE_A(0, 3, 0);
  STAGE_B(1, 0, 0, 1); STAGE_B(1, 0, 1, 1);
  STAGE_B(1, 1, 0, 1); STAGE_B(1, 1, 1, 1);
  VMW(6);
  __builtin_amdgcn_s_barrier();

  const int niter = K >> 7;  // 2 K-tiles (BK=64) per iteration
  for (int it = 0; it < niter; ++it) {
    const int t1 = 2 * it + 1, t2 = 2 * it + 2, t3 = 2 * it + 3;
    const bool nl = (it + 1 < niter);
    // M1: buf0, MH0
    BRD(bfr0, 0, 0);
    ARD(0, 0);
    BRD(bfr1, 0, 1);
    STAGE_A(1, 0, t1); STAGE_A(1, 2, t1);
    STAGE_A(1, 1, t1); STAGE_A(1, 3, t1);
    MFMA32(0);
    VMW(8);
    __builtin_amdgcn_s_barrier();
    // M2: buf0, MH1
    ARD(0, 1);
    MFMA32(1);
    VMW(0);
    __builtin_amdgcn_s_barrier();
    // M3: buf1, MH0
    BRD(bfr0, 1, 0);
    ARD(1, 0);
    BRD(bfr1, 1, 1);
    if (nl) {
      STAGE_B(0, 0, 0, t2); STAGE_B(0, 0, 1, t2);
      STAGE_B(0, 1, 0, t2); STAGE_B(0, 1, 1, t2);
      STAGE_A(0, 0, t2); STAGE_A(0, 2, t2);
    }
    MFMA32(0);
    __builtin_amdgcn_s_barrier();
    // M4: buf1, MH1
    ARD(1, 1);
    if (nl) {
      STAGE_A(0, 1, t2); STAGE_A(0, 3, t2);
      STAGE_B(1, 0, 0, t3); STAGE_B(1, 0, 1, t3);
      STAGE_B(1, 1, 0, t3); STAGE_B(1, 1, 1, t3);
    }
    MFMA32(1);
    VMW(6);
    __builtin_amdgcn_s_barrier();
  }

  // epilogue: C/D layout col=lane&15, row=quad*4+reg (m89-verified)
#pragma unroll
  for (int mi = 0; mi < 8; ++mi) {
    const int row = m0 + wm * 128 + (mi >> 2) * 64 + (mi & 3) * 16 + quad * 4;
#pragma unroll
    for (int j = 0; j < 4; ++j) {
      const int col = n0 + wn * 64 + j * 16 + l15;
      const float bv = bias[col];
#pragma unroll
      for (int r = 0; r < 4; ++r) {
        float v = acc[mi][j][r] + bv;
        if (act) v = fmaxf(v, 0.f);
        C[(size_t)(row + r) * N + col] = f2bf(v);
      }
    }
  }
}

// ---------------------------------------------------------------- head: h@W4+b4, sigmoid
__global__ __launch_bounds__(256) void head_kernel(
    const u16* __restrict__ h, const float2* __restrict__ W4,
    const float* __restrict__ b4, float* __restrict__ out, int H) {
  const int row = blockIdx.x;
  const u16* hr = h + (size_t)row * H;
  const int tid = threadIdx.x;
  float p0 = 0.f, p1 = 0.f;
#pragma unroll
  for (int ii = 0; ii < 2; ++ii) {
    const int base = tid * 16 + ii * 8;  // 8 bf16 per uint4
    const uint4 hv = *(const uint4*)(hr + base);
    const unsigned uu[4] = {hv.x, hv.y, hv.z, hv.w};
#pragma unroll
    for (int j = 0; j < 4; ++j) {
      float a0 = bf2f(uu[j] & 0xffffu);
      float a1 = bf2f(uu[j] >> 16);
      float2 w0 = W4[base + 2 * j];
      float2 w1 = W4[base + 2 * j + 1];
      p0 += a0 * w0.x + a1 * w1.x;
      p1 += a0 * w0.y + a1 * w1.y;
    }
  }
#pragma unroll
  for (int off = 32; off > 0; off >>= 1) {
    p0 += __shfl_down(p0, off, 64);
    p1 += __shfl_down(p1, off, 64);
  }
  __shared__ float r0[4], r1[4];
  const int lane = tid & 63, wave = tid >> 6;
  if (lane == 0) { r0[wave] = p0; r1[wave] = p1; }
  __syncthreads();
  if (tid == 0) {
    float l0 = r0[0] + r0[1] + r0[2] + r0[3] + b4[0];
    float l1 = r1[0] + r1[1] + r1[2] + r1[3] + b4[1];
    out[1 + row * 2] = 1.f / (1.f + __expf(-l0));
    out[2 + row * 2] = 1.f / (1.f + __expf(-l1));
  }
}

// ---------------------------------------------------------------- launch
extern "C" void kernel_launch(void* const* d_in, const int* in_sizes, int n_in,
                              void* d_out, int out_size, void* d_ws,
                              size_t ws_size, hipStream_t stream) {
  (void)in_sizes; (void)n_in; (void)out_size; (void)ws_size;
  const float* x  = (const float*)d_in[0];
  const float* dm = (const float*)d_in[1];
  const float* al = (const float*)d_in[2];
  const float* sl = (const float*)d_in[3];
  const float* sc = (const float*)d_in[4];
  const int*   nd = (const int*)d_in[5];
  const int*   nf = (const int*)d_in[6];
  const float* W1 = (const float*)d_in[7];
  const float* b1 = (const float*)d_in[8];
  const float* W2 = (const float*)d_in[9];
  const float* b2 = (const float*)d_in[10];
  const float* W3 = (const float*)d_in[11];
  const float* b3 = (const float*)d_in[12];
  const float* W4 = (const float*)d_in[13];
  const float* b4 = (const float*)d_in[14];
  float* out = (float*)d_out;

  const int B = 16384, F = 2048, H = 4096, D = 4096, K = 2048;

  // workspace layout (352 MB): xb | wt | hA | hB
  char* ws = (char*)d_ws;
  u16* xb = (u16*)ws;                                         // B*F bf16
  u16* wt = (u16*)(ws + (size_t)B * F * 2);                   // H*H bf16 (reused W1t/W2t/W3t)
  u16* hA = (u16*)(ws + (size_t)B * F * 2 + (size_t)H * H * 2);
  u16* hB = hA + (size_t)B * H;

  // loss
  init_loss_kernel<<<1, 1, 0, stream>>>(sc, nd, nf, out);
  subdom_kernel<<<1024, 256, 0, stream>>>((const float4*)dm, (const float4*)sl,
                                          (const float4*)al, out, D * K / 4,
                                          K / 4 - 1);
  // MLP
  cast_f32_bf16_kernel<<<4096, 256, 0, stream>>>((const float4*)x, xb, B * F / 4);
  transpose_cast_kernel<<<dim3(H / 32, F / 32), dim3(32, 8), 0, stream>>>(W1, wt, F, H);
  gemm256<<<dim3(H / 256, B / 256), 512, 0, stream>>>(xb, wt, b1, hA, B, H, F, 1);
  transpose_cast_kernel<<<dim3(H / 32, H / 32), dim3(32, 8), 0, stream>>>(W2, wt, H, H);
  gemm256<<<dim3(H / 256, B / 256), 512, 0, stream>>>(hA, wt, b2, hB, B, H, H, 1);
  transpose_cast_kernel<<<dim3(H / 32, H / 32), dim3(32, 8), 0, stream>>>(W3, wt, H, H);
  gemm256<<<dim3(H / 256, B / 256), 512, 0, stream>>>(hB, wt, b3, hA, B, H, H, 1);
  head_kernel<<<B, 256, 0, stream>>>(hA, (const float2*)W4, b4, out, H);
}